// Round 11
// baseline (292.217 us; speedup 1.0000x reference)
//
#include <hip/hip_runtime.h>
#include <cmath>

static constexpr int EMB  = 768;
static constexpr int HS   = 64;
static constexpr int NB   = 4;
static constexpr int SEQ  = 4096;
static constexpr int MTOT = NB * SEQ;   // 16384 rows
static constexpr int SPLITS = 8;        // S=12 disproven (R8: reg-file caps 2 blocks/CU)
static constexpr int GRID  = 512;       // exactly 2 blocks/CU x 256 CU -> all co-resident

typedef __attribute__((ext_vector_type(8))) short  short8x;
typedef __attribute__((ext_vector_type(4))) float  float4x;
typedef __attribute__((ext_vector_type(4))) unsigned short ushort4x;

// round-to-nearest-even fp32 -> bf16 bits
__device__ inline unsigned short rne16(float f) {
    unsigned u = __builtin_bit_cast(unsigned, f);
    unsigned r = u + 0x7FFFu + ((u >> 16) & 1u);
    return (unsigned short)(r >> 16);
}
__device__ inline float bf2f(unsigned short h) {
    return __builtin_bit_cast(float, ((unsigned)h) << 16);
}

// ---------------------------------------------------------------------------
// Device-scope sense-reversing grid barrier. Valid because all GRID=512
// blocks are co-resident by construction (LDS 73728 B caps at exactly
// 2 blocks/CU; 512 = 2 x 256 CUs -- R1-R10 ran this shape every round).
// Release-RMW chain on cnt -> release-store sense -> acquire-load sense
// gives cross-XCD visibility of all prior writes (agent scope).
// ---------------------------------------------------------------------------
__device__ inline void grid_barrier(unsigned* cnt, unsigned* sense, unsigned phase) {
    __syncthreads();
    if (threadIdx.x == 0) {
        unsigned arrived = __hip_atomic_fetch_add(cnt, 1u, __ATOMIC_ACQ_REL, __HIP_MEMORY_SCOPE_AGENT);
        if (arrived == GRID - 1) {
            __hip_atomic_store(cnt, 0u, __ATOMIC_RELAXED, __HIP_MEMORY_SCOPE_AGENT);
            __hip_atomic_store(sense, phase, __ATOMIC_RELEASE, __HIP_MEMORY_SCOPE_AGENT);
        } else {
            while (__hip_atomic_load(sense, __ATOMIC_ACQUIRE, __HIP_MEMORY_SCOPE_AGENT) < phase)
                __builtin_amdgcn_s_sleep(2);
        }
    }
    __syncthreads();
}

// ---------------------------------------------------------------------------
// MEGA kernel: convert_w + proj + attn fused (verbatim R10 phase bodies),
// 2 grid barriers replace 2 dispatch boundaries. LDS aliased (proj's
// 4x2304 shorts subset of attn's 8x4608). combine stays separate (wants
// 4 blocks/CU, incompatible with this LDS footprint).
// ---------------------------------------------------------------------------
__global__ __launch_bounds__(256, 2) void mega_kernel(
    const float* __restrict__ x,
    const float* __restrict__ Wk, const float* __restrict__ bk,
    const float* __restrict__ Wq, const float* __restrict__ bq,
    const float* __restrict__ Wv, const float* __restrict__ bv,
    unsigned short* __restrict__ wpk,
    unsigned short* __restrict__ khi, unsigned short* __restrict__ klo,
    unsigned short* __restrict__ qhi, unsigned short* __restrict__ qlo,
    unsigned short* __restrict__ vT,
    float* __restrict__ Opart, float* __restrict__ lpart,
    unsigned* __restrict__ bar_cnt, unsigned* __restrict__ bar_sense)
{
    __shared__ unsigned short smem[8 * 64 * 72];   // 73728 B

    const int tid  = threadIdx.x;
    const int lane = tid & 63;
    const int w    = tid >> 6;
    const int l15  = lane & 15;
    const int quad = lane >> 4;

    // ---------------- phase 1: convert_w (work for gt < 36864) ------------
    {
        const int gt = blockIdx.x * 256 + tid;
        if (gt < 36864) {
            const int cl   = gt & 63;
            const int rest = gt >> 6;       // 0..575
            const int nng  = rest % 12;
            const int kcp  = rest / 12;     // 0..47
            const int kc   = kcp % 24;
            const int p    = kcp / 24;      // 0=hi 1=lo
            const int which= nng >> 2;
            const int nn   = nng & 3;
            const float* W = (which == 0) ? Wk : (which == 1) ? Wq : Wv;
            const int col  = nn * 16 + (cl & 15);
            const int kr   = kc * 32 + (cl >> 4) * 8;
            unsigned short o[8];
            #pragma unroll
            for (int j = 0; j < 8; ++j) {
                float wv = W[(size_t)(kr + j) * HS + col];
                unsigned short h = rne16(wv);
                o[j] = (p == 0) ? h : rne16(wv - bf2f(h));
            }
            size_t base = ((size_t)((p * 24 + kc) * 12 + nng) * 64 + cl) * 8;
            *(short8x*)&wpk[base] = *(short8x*)o;
        }
    }
    grid_barrier(bar_cnt, bar_sense, 1u);

    // ---------------- phase 2: proj (R10 M=32 body, LDS aliased) ----------
    {
        auto xh = (unsigned short (*)[32 * 72])(smem);                 // [2]
        auto xl = (unsigned short (*)[32 * 72])(smem + 2 * 32 * 72);   // [2]
        const int row0 = blockIdx.x * 32;

        float4x acc[3][2] = {};          // [which][mi]
        float4  pre[2];

        #pragma unroll
        for (int it = 0; it < 2; ++it) {
            const int fi = tid + it * 256;
            const int r  = fi >> 4, c4 = (fi & 15) * 4;
            pre[it] = *(const float4*)&x[(size_t)(row0 + r) * EMB + 0 * 64 + c4];
        }
        #pragma unroll
        for (int it = 0; it < 2; ++it) {
            const int fi = tid + it * 256;
            const int r  = fi >> 4, c4 = (fi & 15) * 4;
            const float4 xv = pre[it];
            const unsigned short h0 = rne16(xv.x), h1 = rne16(xv.y),
                                 h2 = rne16(xv.z), h3 = rne16(xv.w);
            ushort4x hv = {h0, h1, h2, h3};
            ushort4x lv = {rne16(xv.x - bf2f(h0)), rne16(xv.y - bf2f(h1)),
                           rne16(xv.z - bf2f(h2)), rne16(xv.w - bf2f(h3))};
            *(ushort4x*)&xh[0][r * 72 + c4] = hv;
            *(ushort4x*)&xl[0][r * 72 + c4] = lv;
        }

        for (int ch = 0; ch < 12; ++ch) {
            if (ch + 1 < 12) {
                #pragma unroll
                for (int it = 0; it < 2; ++it) {
                    const int fi = tid + it * 256;
                    const int r  = fi >> 4, c4 = (fi & 15) * 4;
                    pre[it] = *(const float4*)&x[(size_t)(row0 + r) * EMB + (ch + 1) * 64 + c4];
                }
            }
            __syncthreads();
            const int buf = ch & 1;

            #pragma unroll
            for (int k0i = 0; k0i < 2; ++k0i) {
                const int k0 = k0i * 32;
                const int kc = ch * 2 + k0i;
                short8x ah[2], al[2];
                #pragma unroll
                for (int mi = 0; mi < 2; ++mi) {
                    ah[mi] = *(const short8x*)&xh[buf][(mi * 16 + l15) * 72 + k0 + quad * 8];
                    al[mi] = *(const short8x*)&xl[buf][(mi * 16 + l15) * 72 + k0 + quad * 8];
                }
                #pragma unroll
                for (int which = 0; which < 3; ++which) {
                    const int nng = which * 4 + w;
                    const short8x bh = *(const short8x*)&wpk[((size_t)((0 * 24 + kc) * 12 + nng) * 64 + lane) * 8];
                    const short8x bl = *(const short8x*)&wpk[((size_t)((1 * 24 + kc) * 12 + nng) * 64 + lane) * 8];
                    #pragma unroll
                    for (int mi = 0; mi < 2; ++mi) {
                        acc[which][mi] = __builtin_amdgcn_mfma_f32_16x16x32_bf16(ah[mi], bh, acc[which][mi], 0, 0, 0);
                        acc[which][mi] = __builtin_amdgcn_mfma_f32_16x16x32_bf16(ah[mi], bl, acc[which][mi], 0, 0, 0);
                        acc[which][mi] = __builtin_amdgcn_mfma_f32_16x16x32_bf16(al[mi], bh, acc[which][mi], 0, 0, 0);
                    }
                }
            }

            if (ch + 1 < 12) {
                const int nbuf = (ch + 1) & 1;
                #pragma unroll
                for (int it = 0; it < 2; ++it) {
                    const int fi = tid + it * 256;
                    const int r  = fi >> 4, c4 = (fi & 15) * 4;
                    const float4 xv = pre[it];
                    const unsigned short h0 = rne16(xv.x), h1 = rne16(xv.y),
                                         h2 = rne16(xv.z), h3 = rne16(xv.w);
                    ushort4x hv = {h0, h1, h2, h3};
                    ushort4x lv = {rne16(xv.x - bf2f(h0)), rne16(xv.y - bf2f(h1)),
                                   rne16(xv.z - bf2f(h2)), rne16(xv.w - bf2f(h3))};
                    *(ushort4x*)&xh[nbuf][r * 72 + c4] = hv;
                    *(ushort4x*)&xl[nbuf][r * 72 + c4] = lv;
                }
            }
        }

        const int col = w * 16 + l15;
        const float bkv = bk[col], bqv = bq[col], bvv = bv[col];
        #pragma unroll
        for (int mi = 0; mi < 2; ++mi) {
            const int rbase = row0 + mi * 16 + quad * 4;
            #pragma unroll
            for (int r = 0; r < 4; ++r) {
                const float kv = acc[0][mi][r] + bkv;
                const unsigned short hk = rne16(kv);
                khi[(size_t)(rbase + r) * 64 + col] = hk;
                klo[(size_t)(rbase + r) * 64 + col] = rne16(kv - bf2f(hk));
                const float qv = acc[1][mi][r] + bqv;
                const unsigned short hq = rne16(qv);
                qhi[(size_t)(rbase + r) * 64 + col] = hq;
                qlo[(size_t)(rbase + r) * 64 + col] = rne16(qv - bf2f(hq));
            }
            const int b = rbase / SEQ;
            const int s = rbase % SEQ;
            ushort4x vv = {rne16(acc[2][mi][0] + bvv), rne16(acc[2][mi][1] + bvv),
                           rne16(acc[2][mi][2] + bvv), rne16(acc[2][mi][3] + bvv)};
            *(ushort4x*)&vT[((size_t)b * 64 + col) * SEQ + s] = vv;
        }
    }
    grid_barrier(bar_cnt, bar_sense, 2u);

    // ---------------- phase 3: attn (R10 v14 body, LDS aliased) -----------
    {
        auto qh_s = (unsigned short (*)[64 * 72])(smem);                 // [2]
        auto ql_s = (unsigned short (*)[64 * 72])(smem + 2 * 64 * 72);   // [2]
        auto vt_s = (unsigned short (*)[64 * 72])(smem + 4 * 64 * 72);   // [2]
        unsigned short* psH = smem + 6 * 64 * 72;
        unsigned short* psL = smem + 7 * 64 * 72;

        const int n  = blockIdx.x;                 // 0..511
        const int sp = n & (SPLITS - 1);
        const int b  = (n >> 3) & (NB - 1);
        const int p  = n >> 5;                     // 0..15
        const int jj[4] = {63 - p, 32 + p, 31 - p, p};   // descending j
        const size_t rowb = (size_t)b * SEQ;

        float4x oacc[4][4] = {};                   // [idx][nn]
        float   l_r[4][4]  = {};                   // [idx][r]

        const int sr = tid >> 3;         // staging row 0..31
        const int c8 = (tid & 7) * 8;    // staging col (bf16 units)

        int cur = 0;
        for (int ci = sp; ci <= jj[0]; ci += SPLITS) {
            const int s0 = ci * 64;
            #pragma unroll
            for (int it = 0; it < 2; ++it) {
                const int r = sr + it * 32;
                *(short8x*)&qh_s[cur][r * 72 + c8] = *(const short8x*)&qhi[(rowb + s0 + r) * 64 + c8];
                *(short8x*)&ql_s[cur][r * 72 + c8] = *(const short8x*)&qlo[(rowb + s0 + r) * 64 + c8];
                *(short8x*)&vt_s[cur][r * 72 + c8] = *(const short8x*)&vT[((size_t)b * 64 + r) * SEQ + s0 + c8];
            }
            __syncthreads();
            const unsigned short* qhc = qh_s[cur];
            const unsigned short* qlc = ql_s[cur];
            const unsigned short* vtc = vt_s[cur];
            cur ^= 1;

            #pragma unroll
            for (int g = 0; g < 2; ++g) {
                const int idxH = g ? 1 : 0;        // jj[1]=32+p : jj[0]=63-p
                const int idxL = g ? 2 : 3;        // jj[2]=31-p : jj[3]=p
                const int jH = jj[idxH], jL = jj[idxL];
                const bool aH = (ci <= jH), aL = (ci <= jL);
                if (!aH && !aL) continue;          // wave-uniform

                short8x ahH[2], alH[2], ahL[2], alL[2];
                #pragma unroll
                for (int k0 = 0; k0 < 2; ++k0) {
                    if (aH) {
                        const size_t rH = (rowb + jH * 64 + 16 * w + l15) * 64 + k0 * 32 + quad * 8;
                        ahH[k0] = *(const short8x*)&khi[rH];
                        alH[k0] = *(const short8x*)&klo[rH];
                    }
                    if (aL) {
                        const size_t rL = (rowb + jL * 64 + 16 * w + l15) * 64 + k0 * 32 + quad * 8;
                        ahL[k0] = *(const short8x*)&khi[rL];
                        alL[k0] = *(const short8x*)&klo[rL];
                    }
                }

                float4x sH[4] = {}, sL[4] = {};
                __builtin_amdgcn_s_setprio(1);
                #pragma unroll
                for (int k0 = 0; k0 < 2; ++k0) {
                    #pragma unroll
                    for (int nn = 0; nn < 4; ++nn) {
                        const short8x bh = *(const short8x*)&qhc[(nn * 16 + l15) * 72 + k0 * 32 + quad * 8];
                        const short8x bl = *(const short8x*)&qlc[(nn * 16 + l15) * 72 + k0 * 32 + quad * 8];
                        if (aH) {
                            sH[nn] = __builtin_amdgcn_mfma_f32_16x16x32_bf16(ahH[k0], bh, sH[nn], 0, 0, 0);
                            sH[nn] = __builtin_amdgcn_mfma_f32_16x16x32_bf16(alH[k0], bh, sH[nn], 0, 0, 0);
                            sH[nn] = __builtin_amdgcn_mfma_f32_16x16x32_bf16(ahH[k0], bl, sH[nn], 0, 0, 0);
                        }
                        if (aL) {
                            sL[nn] = __builtin_amdgcn_mfma_f32_16x16x32_bf16(ahL[k0], bh, sL[nn], 0, 0, 0);
                            sL[nn] = __builtin_amdgcn_mfma_f32_16x16x32_bf16(alL[k0], bh, sL[nn], 0, 0, 0);
                            sL[nn] = __builtin_amdgcn_mfma_f32_16x16x32_bf16(ahL[k0], bl, sL[nn], 0, 0, 0);
                        }
                    }
                }
                __builtin_amdgcn_s_setprio(0);

                #pragma unroll
                for (int hl = 0; hl < 2; ++hl) {
                    const bool alive = hl ? aL : aH;
                    if (!alive) continue;
                    const int j   = hl ? jL : jH;
                    const int idx = hl ? idxL : idxH;
                    float4x* sc   = hl ? sL : sH;
                    unsigned short* ps = hl ? psL : psH;
                    if (ci == j) {
                        const int trow = j * 64 + 16 * w + quad * 4;
                        #pragma unroll
                        for (int nn = 0; nn < 4; ++nn) {
                            const int colg = s0 + nn * 16 + l15;
                            #pragma unroll
                            for (int r = 0; r < 4; ++r)
                                if (colg > trow + r) sc[nn][r] = -1e30f;
                        }
                    }
                    #pragma unroll
                    for (int nn = 0; nn < 4; ++nn) {
                        #pragma unroll
                        for (int r = 0; r < 4; ++r) {
                            const float e = __expf(fminf(sc[nn][r], 80.0f));
                            const unsigned short h = rne16(e);
                            l_r[idx][r] += bf2f(h);
                            ps[(16 * w + quad * 4 + r) * 72 + nn * 16 + l15] = h;
                        }
                    }
                }

                __builtin_amdgcn_s_setprio(1);
                #pragma unroll
                for (int k0 = 0; k0 < 2; ++k0) {
                    short8x paH, paL;
                    if (aH) paH = *(const short8x*)&psH[(16 * w + l15) * 72 + k0 * 32 + quad * 8];
                    if (aL) paL = *(const short8x*)&psL[(16 * w + l15) * 72 + k0 * 32 + quad * 8];
                    #pragma unroll
                    for (int nn = 0; nn < 4; ++nn) {
                        const short8x vb = *(const short8x*)&vtc[(nn * 16 + l15) * 72 + k0 * 32 + quad * 8];
                        if (aH) oacc[idxH][nn] = __builtin_amdgcn_mfma_f32_16x16x32_bf16(paH, vb, oacc[idxH][nn], 0, 0, 0);
                        if (aL) oacc[idxL][nn] = __builtin_amdgcn_mfma_f32_16x16x32_bf16(paL, vb, oacc[idxL][nn], 0, 0, 0);
                    }
                }
                __builtin_amdgcn_s_setprio(0);
            }
        }

        // epilogue: per j-tile, reduce l across 16 cols, write fp32 partials
        #pragma unroll
        for (int idx = 0; idx < 4; ++idx) {
            const int j = jj[idx];
            if (idx == 3 && sp > p) continue;      // j0=p never touched by this sp
            float lv[4];
            #pragma unroll
            for (int r = 0; r < 4; ++r) {
                float l = l_r[idx][r];
                l += __shfl_xor(l, 1);
                l += __shfl_xor(l, 2);
                l += __shfl_xor(l, 4);
                l += __shfl_xor(l, 8);
                lv[r] = l;
            }
            const size_t part = (size_t)(j * NB + b) * SPLITS + sp;
            float* Op = Opart + part * 4096;
            #pragma unroll
            for (int nn = 0; nn < 4; ++nn)
                #pragma unroll
                for (int r = 0; r < 4; ++r)
                    Op[(16 * w + quad * 4 + r) * 64 + nn * 16 + l15] = oacc[idx][nn][r];
            if (l15 == 0) {
                #pragma unroll
                for (int r = 0; r < 4; ++r)
                    lpart[part * 64 + 16 * w + quad * 4 + r] = lv[r];
            }
        }
    }
}

// ---------------------------------------------------------------------------
// Combine (unchanged R10): out = (sum_sp O_p) / (sum_sp l_p). Touched-slot
// predicate analytic: slot (j,b,sp) written iff j >= 16 or sp <= j.
// Grid (64, NB, 4): 1024 blocks (4/CU); 1 float4/thread.
// ---------------------------------------------------------------------------
__global__ __launch_bounds__(256) void combine_kernel(
    const float* __restrict__ Opart, const float* __restrict__ lpart,
    float* __restrict__ out)
{
    const int j   = blockIdx.x;
    const int b   = blockIdx.y;
    const int tid = threadIdx.x;
    const int row = blockIdx.z * 16 + (tid >> 4);   // 0..63
    const int c0  = (tid & 15) * 4;
    const size_t base = (size_t)(j * NB + b) * SPLITS;
    const int spmax = (j >= 16) ? SPLITS : ((j < SPLITS ? j : SPLITS - 1) + 1);

    float4 acc = {0.f, 0.f, 0.f, 0.f};
    float lsum = 0.f;
    for (int sp = 0; sp < spmax; ++sp) {
        lsum += lpart[(base + sp) * 64 + row];
        const float4 v = *(const float4*)&Opart[(base + sp) * 4096 + row * 64 + c0];
        acc.x += v.x; acc.y += v.y; acc.z += v.z; acc.w += v.w;
    }
    const float inv = 1.0f / lsum;
    float4 v;
    v.x = acc.x * inv; v.y = acc.y * inv; v.z = acc.z * inv; v.w = acc.w * inv;
    *(float4*)&out[((size_t)b * SEQ + j * 64 + row) * 64 + c0] = v;
}

// ---------------------------------------------------------------------------
extern "C" void kernel_launch(void* const* d_in, const int* in_sizes, int n_in,
                              void* d_out, int out_size, void* d_ws, size_t ws_size,
                              hipStream_t stream)
{
    const float* x  = (const float*)d_in[0];
    const float* Wk = (const float*)d_in[1];
    const float* bk = (const float*)d_in[2];
    const float* Wq = (const float*)d_in[3];
    const float* bq = (const float*)d_in[4];
    const float* Wv = (const float*)d_in[5];
    const float* bv = (const float*)d_in[6];
    float* out = (float*)d_out;

    const size_t NE = (size_t)MTOT * HS;      // 1M elements
    unsigned short* khi = (unsigned short*)d_ws;
    unsigned short* klo = khi + NE;
    unsigned short* qhi = klo + NE;
    unsigned short* qlo = qhi + NE;
    unsigned short* vT  = qlo + NE;
    unsigned short* wpk = vT + NE;            // 294912 shorts
    float* Opart = (float*)(wpk + 294912);
    float* lpart = Opart + (size_t)64 * NB * SPLITS * 4096;
    unsigned* bar = (unsigned*)(lpart + (size_t)64 * NB * SPLITS * 64);
    // ws proven >= 62 MB (R8 ran S=12); this layout needs ~45.6 MB + 8 B.

    hipMemsetAsync(bar, 0, 2 * sizeof(unsigned), stream);
    mega_kernel<<<GRID, 256, 0, stream>>>(x, Wk, bk, Wq, bq, Wv, bv,
                                          wpk, khi, klo, qhi, qlo, vT,
                                          Opart, lpart, bar, bar + 1);
    dim3 cgrid(64, NB, 4);
    combine_kernel<<<cgrid, 256, 0, stream>>>(Opart, lpart, out);
}

// Round 12
// 155.476 us; speedup vs baseline: 1.8795x; 1.8795x over previous
//
#include <hip/hip_runtime.h>
#include <cmath>

static constexpr int EMB  = 768;
static constexpr int HS   = 64;
static constexpr int NB   = 4;
static constexpr int SEQ  = 4096;
static constexpr int MTOT = NB * SEQ;   // 16384 rows
static constexpr int SPLITS = 8;        // S=12 disproven (R8: reg-file caps 2 blocks/CU)

typedef __attribute__((ext_vector_type(8))) short  short8x;
typedef __attribute__((ext_vector_type(4))) float  float4x;
typedef __attribute__((ext_vector_type(4))) unsigned short ushort4x;

// round-to-nearest-even fp32 -> bf16 bits
__device__ inline unsigned short rne16(float f) {
    unsigned u = __builtin_bit_cast(unsigned, f);
    unsigned r = u + 0x7FFFu + ((u >> 16) & 1u);
    return (unsigned short)(r >> 16);
}
__device__ inline float bf2f(unsigned short h) {
    return __builtin_bit_cast(float, ((unsigned)h) << 16);
}

// ---------------------------------------------------------------------------
// Pack Wk/Wq/Wv (fp32 [768][64]) into MFMA B-fragment layout, split hi/lo bf16.
// Layout: [p(2)][kc(24)][nng(12)][lane(64)][j(8)]  (nng = which*4 + nn)
// ---------------------------------------------------------------------------
__global__ __launch_bounds__(256) void convert_w(
    const float* __restrict__ Wk, const float* __restrict__ Wq, const float* __restrict__ Wv,
    unsigned short* __restrict__ wpk)
{
    const int t    = blockIdx.x * 256 + threadIdx.x;  // 0..36863
    const int lane = t & 63;
    const int rest = t >> 6;        // 0..575
    const int nng  = rest % 12;
    const int kcp  = rest / 12;     // 0..47
    const int kc   = kcp % 24;
    const int p    = kcp / 24;      // 0=hi 1=lo
    const int which= nng >> 2;
    const int nn   = nng & 3;
    const float* W = (which == 0) ? Wk : (which == 1) ? Wq : Wv;
    const int col  = nn * 16 + (lane & 15);
    const int kr   = kc * 32 + (lane >> 4) * 8;

    unsigned short o[8];
    #pragma unroll
    for (int j = 0; j < 8; ++j) {
        float w = W[(size_t)(kr + j) * HS + col];
        unsigned short h = rne16(w);
        o[j] = (p == 0) ? h : rne16(w - bf2f(h));
    }
    size_t base = ((size_t)((p * 24 + kc) * 12 + nng) * 64 + lane) * 8;
    *(short8x*)&wpk[base] = *(short8x*)o;
}

// ---------------------------------------------------------------------------
// Projection GEMM (R7-proven M=32 version; R9's M=16 halved wpk-load
// amortization and regressed ~10 us -- occupancy was NOT proj's binding
// constraint). 32-row tiles, double-buffered x staging, 3-pass split-bf16.
// Outputs khi/klo/qhi/qlo bf16 [16384][64]; vT bf16 [4][64][4096].
// ---------------------------------------------------------------------------
__global__ __launch_bounds__(256) void proj_kernel(
    const float* __restrict__ x,
    const unsigned short* __restrict__ wpk,
    const float* __restrict__ bk, const float* __restrict__ bq, const float* __restrict__ bv,
    unsigned short* __restrict__ khi, unsigned short* __restrict__ klo,
    unsigned short* __restrict__ qhi, unsigned short* __restrict__ qlo,
    unsigned short* __restrict__ vT)
{
    __shared__ unsigned short xh[2][32 * 72];
    __shared__ unsigned short xl[2][32 * 72];

    const int tid  = threadIdx.x;
    const int lane = tid & 63;
    const int w    = tid >> 6;       // wave 0..3 -> nn stripe
    const int l15  = lane & 15;
    const int quad = lane >> 4;
    const int row0 = blockIdx.x * 32;

    float4x acc[3][2] = {};          // [which][mi]
    float4  pre[2];

    #pragma unroll
    for (int it = 0; it < 2; ++it) {
        const int fi = tid + it * 256;
        const int r  = fi >> 4, c4 = (fi & 15) * 4;
        pre[it] = *(const float4*)&x[(size_t)(row0 + r) * EMB + 0 * 64 + c4];
    }
    #pragma unroll
    for (int it = 0; it < 2; ++it) {
        const int fi = tid + it * 256;
        const int r  = fi >> 4, c4 = (fi & 15) * 4;
        const float4 xv = pre[it];
        const unsigned short h0 = rne16(xv.x), h1 = rne16(xv.y),
                             h2 = rne16(xv.z), h3 = rne16(xv.w);
        ushort4x hv = {h0, h1, h2, h3};
        ushort4x lv = {rne16(xv.x - bf2f(h0)), rne16(xv.y - bf2f(h1)),
                       rne16(xv.z - bf2f(h2)), rne16(xv.w - bf2f(h3))};
        *(ushort4x*)&xh[0][r * 72 + c4] = hv;
        *(ushort4x*)&xl[0][r * 72 + c4] = lv;
    }

    for (int ch = 0; ch < 12; ++ch) {
        if (ch + 1 < 12) {
            #pragma unroll
            for (int it = 0; it < 2; ++it) {
                const int fi = tid + it * 256;
                const int r  = fi >> 4, c4 = (fi & 15) * 4;
                pre[it] = *(const float4*)&x[(size_t)(row0 + r) * EMB + (ch + 1) * 64 + c4];
            }
        }
        __syncthreads();
        const int buf = ch & 1;

        #pragma unroll
        for (int k0i = 0; k0i < 2; ++k0i) {
            const int k0 = k0i * 32;
            const int kc = ch * 2 + k0i;
            short8x ah[2], al[2];
            #pragma unroll
            for (int mi = 0; mi < 2; ++mi) {
                ah[mi] = *(const short8x*)&xh[buf][(mi * 16 + l15) * 72 + k0 + quad * 8];
                al[mi] = *(const short8x*)&xl[buf][(mi * 16 + l15) * 72 + k0 + quad * 8];
            }
            #pragma unroll
            for (int which = 0; which < 3; ++which) {
                const int nng = which * 4 + w;
                const short8x bh = *(const short8x*)&wpk[((size_t)((0 * 24 + kc) * 12 + nng) * 64 + lane) * 8];
                const short8x bl = *(const short8x*)&wpk[((size_t)((1 * 24 + kc) * 12 + nng) * 64 + lane) * 8];
                #pragma unroll
                for (int mi = 0; mi < 2; ++mi) {
                    acc[which][mi] = __builtin_amdgcn_mfma_f32_16x16x32_bf16(ah[mi], bh, acc[which][mi], 0, 0, 0);
                    acc[which][mi] = __builtin_amdgcn_mfma_f32_16x16x32_bf16(ah[mi], bl, acc[which][mi], 0, 0, 0);
                    acc[which][mi] = __builtin_amdgcn_mfma_f32_16x16x32_bf16(al[mi], bh, acc[which][mi], 0, 0, 0);
                }
            }
        }

        if (ch + 1 < 12) {
            const int nbuf = (ch + 1) & 1;
            #pragma unroll
            for (int it = 0; it < 2; ++it) {
                const int fi = tid + it * 256;
                const int r  = fi >> 4, c4 = (fi & 15) * 4;
                const float4 xv = pre[it];
                const unsigned short h0 = rne16(xv.x), h1 = rne16(xv.y),
                                     h2 = rne16(xv.z), h3 = rne16(xv.w);
                ushort4x hv = {h0, h1, h2, h3};
                ushort4x lv = {rne16(xv.x - bf2f(h0)), rne16(xv.y - bf2f(h1)),
                               rne16(xv.z - bf2f(h2)), rne16(xv.w - bf2f(h3))};
                *(ushort4x*)&xh[nbuf][r * 72 + c4] = hv;
                *(ushort4x*)&xl[nbuf][r * 72 + c4] = lv;
            }
        }
    }

    const int col = w * 16 + l15;
    const float bkv = bk[col], bqv = bq[col], bvv = bv[col];
    #pragma unroll
    for (int mi = 0; mi < 2; ++mi) {
        const int rbase = row0 + mi * 16 + quad * 4;
        #pragma unroll
        for (int r = 0; r < 4; ++r) {
            const float kv = acc[0][mi][r] + bkv;
            const unsigned short hk = rne16(kv);
            khi[(size_t)(rbase + r) * 64 + col] = hk;
            klo[(size_t)(rbase + r) * 64 + col] = rne16(kv - bf2f(hk));
            const float qv = acc[1][mi][r] + bqv;
            const unsigned short hq = rne16(qv);
            qhi[(size_t)(rbase + r) * 64 + col] = hq;
            qlo[(size_t)(rbase + r) * 64 + col] = rne16(qv - bf2f(hq));
        }
        const int b = rbase / SEQ;
        const int s = rbase % SEQ;
        ushort4x vv = {rne16(acc[2][mi][0] + bvv), rne16(acc[2][mi][1] + bvv),
                       rne16(acc[2][mi][2] + bvv), rne16(acc[2][mi][3] + bvv)};
        *(ushort4x*)&vT[((size_t)b * 64 + col) * SEQ + s] = vv;
    }
}

// ---------------------------------------------------------------------------
// Flash attention v14 (R9/R10-proven, 43.2 us): v7 compute body + ping-pong
// LDS double-buffer, ONE barrier per iteration, NO cross-barrier register
// state:  iter t: stage tile_t -> buf[t&1]; barrier; compute buf[t&1]
// Safety: buf[t&1]'s prior readers (compute t-2) finished before
// barrier_{t-1}, which precedes stage_t. LDS 73728 B, 2 blocks/CU.
// R11 note: fusing phases into one kernel regressed 2.8x (codegen coupling)
// -- separate dispatches ARE part of the optimum.
// ---------------------------------------------------------------------------
__global__ __launch_bounds__(256, 2) void attn_kernel(
    const unsigned short* __restrict__ khi, const unsigned short* __restrict__ klo,
    const unsigned short* __restrict__ qhi, const unsigned short* __restrict__ qlo,
    const unsigned short* __restrict__ vT,
    float* __restrict__ Opart, float* __restrict__ lpart)
{
    __shared__ unsigned short qh_s[2][64 * 72];   // K-role hi tile [s][h]
    __shared__ unsigned short ql_s[2][64 * 72];   // K-role lo tile [s][h]
    __shared__ unsigned short vt_s[2][64 * 72];   // V tile [h][s]
    __shared__ unsigned short psH[64 * 72];       // P tiles (intra-wave rows)
    __shared__ unsigned short psL[64 * 72];

    const int tid  = threadIdx.x;
    const int lane = tid & 63;
    const int w    = tid >> 6;
    const int l15  = lane & 15;
    const int quad = lane >> 4;

    const int n  = blockIdx.x;                 // 0..511
    const int sp = n & (SPLITS - 1);
    const int b  = (n >> 3) & (NB - 1);
    const int p  = n >> 5;                     // 0..15
    const int jj[4] = {63 - p, 32 + p, 31 - p, p};   // descending j
    const size_t rowb = (size_t)b * SEQ;

    float4x oacc[4][4] = {};                   // [idx][nn]
    float   l_r[4][4]  = {};                   // [idx][r]

    const int sr = tid >> 3;         // staging row 0..31
    const int c8 = (tid & 7) * 8;    // staging col (bf16 units)

    int cur = 0;
    for (int ci = sp; ci <= jj[0]; ci += SPLITS) {
        const int s0 = ci * 64;
        // stage tile(ci) into buf[cur]; prior readers of buf[cur] (iter t-2)
        // finished before the barrier of iter t-1 -> safe without a barrier.
        #pragma unroll
        for (int it = 0; it < 2; ++it) {
            const int r = sr + it * 32;
            *(short8x*)&qh_s[cur][r * 72 + c8] = *(const short8x*)&qhi[(rowb + s0 + r) * 64 + c8];
            *(short8x*)&ql_s[cur][r * 72 + c8] = *(const short8x*)&qlo[(rowb + s0 + r) * 64 + c8];
            *(short8x*)&vt_s[cur][r * 72 + c8] = *(const short8x*)&vT[((size_t)b * 64 + r) * SEQ + s0 + c8];
        }
        __syncthreads();
        const unsigned short* qhc = qh_s[cur];
        const unsigned short* qlc = ql_s[cur];
        const unsigned short* vtc = vt_s[cur];
        cur ^= 1;

        #pragma unroll
        for (int g = 0; g < 2; ++g) {
            const int idxH = g ? 1 : 0;        // jj[1]=32+p : jj[0]=63-p
            const int idxL = g ? 2 : 3;        // jj[2]=31-p : jj[3]=p
            const int jH = jj[idxH], jL = jj[idxL];
            const bool aH = (ci <= jH), aL = (ci <= jL);
            if (!aH && !aL) continue;          // wave-uniform

            // A-frags from global, transient (L2-hot: khi/klo are 2 MB each)
            short8x ahH[2], alH[2], ahL[2], alL[2];
            #pragma unroll
            for (int k0 = 0; k0 < 2; ++k0) {
                if (aH) {
                    const size_t rH = (rowb + jH * 64 + 16 * w + l15) * 64 + k0 * 32 + quad * 8;
                    ahH[k0] = *(const short8x*)&khi[rH];
                    alH[k0] = *(const short8x*)&klo[rH];
                }
                if (aL) {
                    const size_t rL = (rowb + jL * 64 + 16 * w + l15) * 64 + k0 * 32 + quad * 8;
                    ahL[k0] = *(const short8x*)&khi[rL];
                    alL[k0] = *(const short8x*)&klo[rL];
                }
            }

            // S = Qrole . KroleT, 3-pass split; B-frags read once for both j's
            float4x sH[4] = {}, sL[4] = {};
            __builtin_amdgcn_s_setprio(1);
            #pragma unroll
            for (int k0 = 0; k0 < 2; ++k0) {
                #pragma unroll
                for (int nn = 0; nn < 4; ++nn) {
                    const short8x bh = *(const short8x*)&qhc[(nn * 16 + l15) * 72 + k0 * 32 + quad * 8];
                    const short8x bl = *(const short8x*)&qlc[(nn * 16 + l15) * 72 + k0 * 32 + quad * 8];
                    if (aH) {
                        sH[nn] = __builtin_amdgcn_mfma_f32_16x16x32_bf16(ahH[k0], bh, sH[nn], 0, 0, 0);
                        sH[nn] = __builtin_amdgcn_mfma_f32_16x16x32_bf16(alH[k0], bh, sH[nn], 0, 0, 0);
                        sH[nn] = __builtin_amdgcn_mfma_f32_16x16x32_bf16(ahH[k0], bl, sH[nn], 0, 0, 0);
                    }
                    if (aL) {
                        sL[nn] = __builtin_amdgcn_mfma_f32_16x16x32_bf16(ahL[k0], bh, sL[nn], 0, 0, 0);
                        sL[nn] = __builtin_amdgcn_mfma_f32_16x16x32_bf16(alL[k0], bh, sL[nn], 0, 0, 0);
                        sL[nn] = __builtin_amdgcn_mfma_f32_16x16x32_bf16(ahL[k0], bl, sL[nn], 0, 0, 0);
                    }
                }
            }
            __builtin_amdgcn_s_setprio(0);

            // mask diag tile, exp, write P tiles, accumulate l
            #pragma unroll
            for (int hl = 0; hl < 2; ++hl) {
                const bool alive = hl ? aL : aH;
                if (!alive) continue;
                const int j   = hl ? jL : jH;
                const int idx = hl ? idxL : idxH;
                float4x* sc   = hl ? sL : sH;
                unsigned short* ps = hl ? psL : psH;
                if (ci == j) {
                    const int trow = j * 64 + 16 * w + quad * 4;
                    #pragma unroll
                    for (int nn = 0; nn < 4; ++nn) {
                        const int colg = s0 + nn * 16 + l15;
                        #pragma unroll
                        for (int r = 0; r < 4; ++r)
                            if (colg > trow + r) sc[nn][r] = -1e30f;
                    }
                }
                #pragma unroll
                for (int nn = 0; nn < 4; ++nn) {
                    #pragma unroll
                    for (int r = 0; r < 4; ++r) {
                        const float e = __expf(fminf(sc[nn][r], 80.0f));
                        const unsigned short h = rne16(e);
                        l_r[idx][r] += bf2f(h);
                        ps[(16 * w + quad * 4 + r) * 72 + nn * 16 + l15] = h;
                    }
                }
            }

            // PV: V-frags read once for both j's (ps same-wave -> no barrier)
            __builtin_amdgcn_s_setprio(1);
            #pragma unroll
            for (int k0 = 0; k0 < 2; ++k0) {
                short8x paH, paL;
                if (aH) paH = *(const short8x*)&psH[(16 * w + l15) * 72 + k0 * 32 + quad * 8];
                if (aL) paL = *(const short8x*)&psL[(16 * w + l15) * 72 + k0 * 32 + quad * 8];
                #pragma unroll
                for (int nn = 0; nn < 4; ++nn) {
                    const short8x vb = *(const short8x*)&vtc[(nn * 16 + l15) * 72 + k0 * 32 + quad * 8];
                    if (aH) oacc[idxH][nn] = __builtin_amdgcn_mfma_f32_16x16x32_bf16(paH, vb, oacc[idxH][nn], 0, 0, 0);
                    if (aL) oacc[idxL][nn] = __builtin_amdgcn_mfma_f32_16x16x32_bf16(paL, vb, oacc[idxL][nn], 0, 0, 0);
                }
            }
            __builtin_amdgcn_s_setprio(0);
        }
    }

    // epilogue: per j-tile, reduce l across 16 cols, write fp32 partials
    #pragma unroll
    for (int idx = 0; idx < 4; ++idx) {
        const int j = jj[idx];
        if (idx == 3 && sp > p) continue;      // j0=p never touched by this sp
        float lv[4];
        #pragma unroll
        for (int r = 0; r < 4; ++r) {
            float l = l_r[idx][r];
            l += __shfl_xor(l, 1);
            l += __shfl_xor(l, 2);
            l += __shfl_xor(l, 4);
            l += __shfl_xor(l, 8);
            lv[r] = l;
        }
        const size_t part = (size_t)(j * NB + b) * SPLITS + sp;
        float* Op = Opart + part * 4096;
        #pragma unroll
        for (int nn = 0; nn < 4; ++nn)
            #pragma unroll
            for (int r = 0; r < 4; ++r)
                Op[(16 * w + quad * 4 + r) * 64 + nn * 16 + l15] = oacc[idx][nn][r];
        if (l15 == 0) {
            #pragma unroll
            for (int r = 0; r < 4; ++r)
                lpart[part * 64 + 16 * w + quad * 4 + r] = lv[r];
        }
    }
}

// ---------------------------------------------------------------------------
// Combine: out = (sum_sp O_p) / (sum_sp l_p). Touched-slot predicate computed
// analytically: slot (j,b,sp) written iff j >= 16 (always) or sp <= j; l>0
// guaranteed on touched slots. No memset needed (R7-proven).
// Grid (64, NB, 4): 1024 blocks (4/CU); 1 float4/thread.
// ---------------------------------------------------------------------------
__global__ __launch_bounds__(256) void combine_kernel(
    const float* __restrict__ Opart, const float* __restrict__ lpart,
    float* __restrict__ out)
{
    const int j   = blockIdx.x;
    const int b   = blockIdx.y;
    const int tid = threadIdx.x;
    const int row = blockIdx.z * 16 + (tid >> 4);   // 0..63
    const int c0  = (tid & 15) * 4;
    const size_t base = (size_t)(j * NB + b) * SPLITS;
    const int spmax = (j >= 16) ? SPLITS : ((j < SPLITS ? j : SPLITS - 1) + 1);

    float4 acc = {0.f, 0.f, 0.f, 0.f};
    float lsum = 0.f;
    for (int sp = 0; sp < spmax; ++sp) {
        lsum += lpart[(base + sp) * 64 + row];
        const float4 v = *(const float4*)&Opart[(base + sp) * 4096 + row * 64 + c0];
        acc.x += v.x; acc.y += v.y; acc.z += v.z; acc.w += v.w;
    }
    const float inv = 1.0f / lsum;
    float4 v;
    v.x = acc.x * inv; v.y = acc.y * inv; v.z = acc.z * inv; v.w = acc.w * inv;
    *(float4*)&out[((size_t)b * SEQ + j * 64 + row) * 64 + c0] = v;
}

// ---------------------------------------------------------------------------
extern "C" void kernel_launch(void* const* d_in, const int* in_sizes, int n_in,
                              void* d_out, int out_size, void* d_ws, size_t ws_size,
                              hipStream_t stream)
{
    const float* x  = (const float*)d_in[0];
    const float* Wk = (const float*)d_in[1];
    const float* bk = (const float*)d_in[2];
    const float* Wq = (const float*)d_in[3];
    const float* bq = (const float*)d_in[4];
    const float* Wv = (const float*)d_in[5];
    const float* bv = (const float*)d_in[6];
    float* out = (float*)d_out;

    const size_t NE = (size_t)MTOT * HS;      // 1M elements
    unsigned short* khi = (unsigned short*)d_ws;
    unsigned short* klo = khi + NE;
    unsigned short* qhi = klo + NE;
    unsigned short* qlo = qhi + NE;
    unsigned short* vT  = qlo + NE;
    unsigned short* wpk = vT + NE;            // 294912 shorts
    float* Opart = (float*)(wpk + 294912);
    float* lpart = Opart + (size_t)64 * NB * SPLITS * 4096;
    // total ~45.6 MB (proven)

    convert_w<<<144, 256, 0, stream>>>(Wk, Wq, Wv, wpk);
    proj_kernel<<<MTOT / 32, 256, 0, stream>>>(x, wpk, bk, bq, bv, khi, klo, qhi, qlo, vT);
    attn_kernel<<<16 * NB * SPLITS, 256, 0, stream>>>(khi, klo, qhi, qlo, vT, Opart, lpart);
    dim3 cgrid(64, NB, 4);
    combine_kernel<<<cgrid, 256, 0, stream>>>(Opart, lpart, out);
}